// Round 1
// 1937.396 us; speedup vs baseline: 1.1236x; 1.1236x over previous
//
#include <hip/hip_runtime.h>
#include <hip/hip_bf16.h>
#include <cstdint>
#include <cstddef>

// ---------------- problem constants ----------------
constexpr int BB    = 8;
constexpr int NV    = 2048;
constexpr int NF    = 4096;
constexpr int NE    = 12288;
constexpr int DIM   = 512;
constexpr int DCB   = 192;
constexpr int NQv   = 2;
constexpr int BITSv = 14;
constexpr int NFACE = BB * NF;        // 32768
constexpr int NEDGE = BB * NE;        // 98304
constexpr int NVB   = BB * NV;        // 16384
constexpr int NFP   = NF + 2;         // padded rows per batch (conv guards)

typedef __attribute__((ext_vector_type(8))) short bf16x8;
typedef __attribute__((ext_vector_type(4))) float f32x4;

static __device__ __forceinline__ float b2f(unsigned short u) {
    union { unsigned u; float f; } x; x.u = ((unsigned)u) << 16; return x.f;
}
static __device__ __forceinline__ unsigned short f2bu(float v) {
    __hip_bfloat16 h = __float2bfloat16(v);
    return __builtin_bit_cast(unsigned short, h);
}
// exact-to-~2^-25 three-plane bf16 split (24 mantissa bits ~ f32)
static __device__ __forceinline__ void split3(float v, unsigned short& a, unsigned short& b,
                                              unsigned short& c) {
    a = f2bu(v);            float r  = v - b2f(a);
    b = f2bu(r);            float r2 = r - b2f(b);
    c = f2bu(r2);
}
static __device__ __forceinline__ void load16(const void* g, void* l) {
    __builtin_amdgcn_global_load_lds((const __attribute__((address_space(1))) unsigned int*)g,
                                     (__attribute__((address_space(3))) unsigned int*)l, 16, 0, 0);
}

// XCD-bijective swizzle for GEMM grids of shape (nx, 256), nx*256 % 8 == 0.
// HW round-robins flattened wg id across 8 XCDs (xcd = lin & 7). Remap so the
// nx n-blocks sharing an A row-tile get consecutive j -> SAME xcd -> A fetched
// from HBM once per XCD instead of nx times (measured 783 MB ~= 4x201 MB on
// k_mm_enc without this). Bijective: by = xcd*32 + j/nx covers [0,256).
static __device__ __forceinline__ void xcd_swizzle(int& bx, int& by)
{
    const int nx  = (int)gridDim.x;
    const int lin = (int)(blockIdx.x + gridDim.x * blockIdx.y);
    const int xcd = lin & 7;
    const int j   = lin >> 3;          // [0, 32*nx)
    bx = j % nx;
    by = xcd * 32 + j / nx;
}

// ---------------- codes: disc vertex coords per face corner -> fc [NFACE][12] ----------------
__global__ void k_codes(const float* __restrict__ vertices, const int* __restrict__ faces,
                        int* __restrict__ fc)
{
    const int idx = blockIdx.x * 256 + threadIdx.x;   // NFACE*9
    if (idx >= NFACE * 9) return;
    const int r = idx / 9, p = idx - r * 9;
    const int i = p / 3, j = p - i * 3;
    const int b = r >> 12;
    const int v = faces[r * 3 + i];
    const float coord = vertices[((size_t)b * NV + v) * 3 + j];
    float t = rintf((coord + 1.0f) * 0.5f * 128.0f - 0.5f);
    t = fminf(fmaxf(t, 0.0f), 127.0f);
    fc[r * 12 + p] = (int)t;
}

// ---------------- T table: T[p][c][o] = sum_d ce[c][d] * W_in[p*64+d][o] ----------------
__global__ __launch_bounds__(256)
void k_build_T(const float* __restrict__ ce, const float* __restrict__ W_in, float* __restrict__ T)
{
    const int p = blockIdx.x;      // 0..8
    const int c = blockIdx.y;      // 0..127
    const int o = threadIdx.x * 2;
    float s0 = 0.f, s1 = 0.f;
    for (int d = 0; d < 64; ++d) {
        const float e = ce[c * 64 + d];
        const float* wr_ = W_in + (size_t)(p * 64 + d) * 512 + o;
        s0 = fmaf(e, wr_[0], s0);
        s1 = fmaf(e, wr_[1], s1);
    }
    float* dst = T + ((size_t)p * 128 + c) * 512 + o;
    dst[0] = s0; dst[1] = s1;
}

// ---------------- x = b_in + sum_p T[p][fc[r][p]]  -> 3 bf16 planes ----------------
__global__ __launch_bounds__(256)
void k_xin(const int* __restrict__ fc, const float* __restrict__ T,
           const float* __restrict__ b_in,
           unsigned short* __restrict__ x0, unsigned short* __restrict__ x1,
           unsigned short* __restrict__ x2)
{
    const int r = blockIdx.x;          // 0..NFACE-1
    const int o = threadIdx.x * 2;
    float s0 = b_in[o], s1 = b_in[o + 1];
#pragma unroll
    for (int p = 0; p < 9; ++p) {
        const int c = fc[r * 12 + p];
        const float* t = T + ((size_t)p * 128 + c) * 512 + o;
        s0 += t[0]; s1 += t[1];
    }
    unsigned short h0, m0, l0, h1, m1, l1;
    split3(s0, h0, m0, l0); split3(s1, h1, m1, l1);
    const size_t ob = (size_t)r * 512 + o;
    ushort2 u;
    u.x = h0; u.y = h1; *(ushort2*)&x0[ob] = u;
    u.x = m0; u.y = m1; *(ushort2*)&x1[ob] = u;
    u.x = l0; u.y = l1; *(ushort2*)&x2[ob] = u;
}

// ---------------- CSR build ----------------
__global__ void k_count_e(const int* __restrict__ fe, int* __restrict__ deg)
{
    const int e = blockIdx.x * 256 + threadIdx.x;
    if (e >= NEDGE) return;
    const int b = e / NE, ee = e - b * NE;
    atomicAdd(&deg[fe[(b * 2 + 1) * NE + ee] + b * NF], 1);
}
__global__ void k_fill_e(const int* __restrict__ fe, int* __restrict__ cursor, int* __restrict__ srcE)
{
    const int e = blockIdx.x * 256 + threadIdx.x;
    if (e >= NEDGE) return;
    const int b = e / NE, ee = e - b * NE;
    const int src = fe[(b * 2 + 0) * NE + ee] + b * NF;
    const int tgt = fe[(b * 2 + 1) * NE + ee] + b * NF;
    srcE[atomicAdd(&cursor[tgt], 1)] = src;
}
__global__ void k_count_v(const int* __restrict__ faces, int* __restrict__ deg)
{
    const int q = blockIdx.x * 256 + threadIdx.x;
    if (q >= NEDGE) return;                  // NFACE*3 == 98304
    atomicAdd(&deg[(q / (NF * 3)) * NV + faces[q]], 1);
}
__global__ void k_fill_v(const int* __restrict__ faces, int* __restrict__ cursor, int* __restrict__ cid)
{
    const int q = blockIdx.x * 256 + threadIdx.x;
    if (q >= NEDGE) return;
    const int b = q / (NF * 3);
    cid[atomicAdd(&cursor[b * NV + faces[q]], 1)] = q;
}
__global__ void k_scan(const int* __restrict__ deg, int* __restrict__ rowstart,
                       int* __restrict__ cursor, int n)
{
    __shared__ int part[256];
    const int t = threadIdx.x;
    const int chunk = n / 256;
    int s = 0;
    for (int i = 0; i < chunk; ++i) s += deg[t * chunk + i];
    part[t] = s;
    __syncthreads();
    for (int o = 1; o < 256; o <<= 1) {
        int v = (t >= o) ? part[t - o] : 0;
        __syncthreads();
        part[t] += v;
        __syncthreads();
    }
    int base = (t == 0) ? 0 : part[t - 1];
    for (int i = 0; i < chunk; ++i) {
        const int idx = t * chunk + i;
        const int d = deg[idx];
        rowstart[idx] = base;
        cursor[idx]   = base;
        base += d;
    }
    if (t == 255) rowstart[n] = base;
}

// ---------------- edge gather-mean on 3-plane bf16, exact reconstruct + split3 out ---------
__global__ void k_agg_e3(const unsigned short* __restrict__ p0, const unsigned short* __restrict__ p1,
                         const unsigned short* __restrict__ p2, const int* __restrict__ rowstart,
                         const int* __restrict__ srcE,
                         unsigned short* __restrict__ o0, unsigned short* __restrict__ o1,
                         unsigned short* __restrict__ o2)
{
    const int t = threadIdx.x;
    const int r = blockIdx.x * 2 + (t >> 7);
    const int c4 = (t & 127) << 2;
    const int s = rowstart[r], e = rowstart[r + 1];
    float a0 = 0.f, a1 = 0.f, a2 = 0.f, a3 = 0.f;
    for (int i = s; i < e; ++i) {
        const size_t ba = (size_t)srcE[i] * 512 + c4;
        const ushort4 u0 = *(const ushort4*)(p0 + ba);
        const ushort4 u1 = *(const ushort4*)(p1 + ba);
        const ushort4 u2 = *(const ushort4*)(p2 + ba);
        a0 += b2f(u0.x) + b2f(u1.x) + b2f(u2.x);
        a1 += b2f(u0.y) + b2f(u1.y) + b2f(u2.y);
        a2 += b2f(u0.z) + b2f(u1.z) + b2f(u2.z);
        a3 += b2f(u0.w) + b2f(u1.w) + b2f(u2.w);
    }
    const float inv = 1.0f / fmaxf((float)(e - s), 1.0f);
    a0 *= inv; a1 *= inv; a2 *= inv; a3 *= inv;
    ushort4 q0, q1, q2;
    split3(a0, q0.x, q1.x, q2.x); split3(a1, q0.y, q1.y, q2.y);
    split3(a2, q0.z, q1.z, q2.z); split3(a3, q0.w, q1.w, q2.w);
    const size_t ob = (size_t)r * 512 + c4;
    *(ushort4*)(o0 + ob) = q0; *(ushort4*)(o1 + ob) = q1; *(ushort4*)(o2 + ob) = q2;
}

// ---------------- vertex gather-mean: fe [NFACE,576] f32 -> avg [NVB,192] ----------------
__global__ void k_agg_verts(const float* __restrict__ fe, const int* __restrict__ rowstart,
                            const int* __restrict__ cid, float* __restrict__ avg)
{
    const int r = blockIdx.x;       // 0..NVB-1
    const int c = threadIdx.x;      // 192
    const int s = rowstart[r], e = rowstart[r + 1];
    float a = 0.f;
    for (int i = s; i < e; ++i) {
        const int q = cid[i];
        const int face = q / 3, corner = q - face * 3;
        a += fe[(size_t)face * 576 + corner * 192 + c];
    }
    avg[(size_t)r * 192 + c] = a / fmaxf((float)(e - s), 1e-5f);
}

// ---------------- residual LFQ (f32) ----------------
__global__ void k_lfq(const float* __restrict__ avg, const float* __restrict__ lfq_in,
                      const float* __restrict__ lfq_out, float* __restrict__ quant)
{
    __shared__ float res[DCB];
    __shared__ float qacc[DCB];
    __shared__ float bits[BITSv];
    const int r = blockIdx.x;
    const int t = threadIdx.x;     // 64
    for (int c = t; c < DCB; c += 64) {
        res[c]  = avg[(size_t)r * DCB + c];
        qacc[c] = 0.f;
    }
    __syncthreads();
    for (int q = 0; q < NQv; ++q) {
        if (t < BITSv) {
            float h = 0.f;
            const float* w = lfq_in + q * DCB * BITSv + t;
            for (int k = 0; k < DCB; ++k) h += res[k] * w[k * BITSv];
            bits[t] = (h > 0.f) ? 1.f : -1.f;
        }
        __syncthreads();
        for (int c = t; c < DCB; c += 64) {
            float o = 0.f;
            const float* w2 = lfq_out + q * BITSv * DCB + c;
#pragma unroll
            for (int j = 0; j < BITSv; ++j) o += bits[j] * w2[j * DCB];
            qacc[c] += o;
            res[c]  -= o;
        }
        __syncthreads();
    }
    for (int c = t; c < DCB; c += 64) quant[(size_t)r * DCB + c] = qacc[c];
}

// ---------------- gather quant back to faces -> feo bf16 [NFACE,576] ----------------
__global__ void k_gather_feo(const float* __restrict__ quant, const int* __restrict__ faces,
                             unsigned short* __restrict__ feo)
{
    const long long idx = (long long)blockIdx.x * 256 + threadIdx.x;
    if (idx >= (long long)NFACE * 576) return;
    const int row = (int)(idx / 576);
    const int col = (int)(idx - (long long)row * 576);
    const int i = col / 192, c = col - i * 192;
    const int b = row >> 12;
    const int v = faces[row * 3 + i];
    feo[idx] = f2bu(quant[((size_t)b * NV + v) * 192 + c]);
}

// ---------------- weight packing ----------------
__global__ void k_pack_plain(const float* __restrict__ src, unsigned short* __restrict__ dst,
                             int Kd, int Nd)
{
    const int idx = blockIdx.x * 256 + threadIdx.x;
    if (idx >= Kd * Nd) return;
    const int n = idx / Kd, k = idx - n * Kd;
    dst[idx] = f2bu(src[(size_t)k * Nd + n]);
}
__global__ void k_pack_conv(const float* __restrict__ w, unsigned short* __restrict__ bt)
{
    const int idx = blockIdx.x * 256 + threadIdx.x;   // 4*512*1536
    if (idx >= 4 * 512 * 1536) return;
    const int ws_ = idx / (512 * 1536);
    const int rem = idx - ws_ * 512 * 1536;
    const int o = rem / 1536, k = rem - o * 1536;
    const int tap = k >> 9, i = k & 511;
    bt[idx] = f2bu(w[(((size_t)(ws_ * 512 + o)) * 512 + i) * 3 + tap]);
}
// B-plane select for seg pattern {0,1,0,2,1,0} (pairs A {0,0,1,0,1,2})
static __device__ __forceinline__ unsigned short bplane(float w, int inner)
{
    unsigned short w0, w1, w2; split3(w, w0, w1, w2);
    const int bsel = (inner == 3) ? 2 : ((inner == 1 || inner == 4) ? 1 : 0);
    return (bsel == 0) ? w0 : ((bsel == 1) ? w1 : w2);
}
// sage layer l: Bt[l][n in 512][k in 6144]: segs 0-5 = Wl planes, 6-11 = Wr planes
__global__ void k_pack_sage3(const float* __restrict__ wl, const float* __restrict__ wr,
                             unsigned short* __restrict__ bt)
{
    const int idx = blockIdx.x * 256 + threadIdx.x;   // 2*512*6144
    if (idx >= 2 * 512 * 6144) return;
    const int l = idx / (512 * 6144);
    const int rem = idx - l * 512 * 6144;
    const int n = rem / 6144, k = rem - n * 6144;
    const int seg = k >> 9, kk = k & 511;
    const int inner = (seg >= 6) ? seg - 6 : seg;
    const float* W = ((seg >= 6) ? wr : wl) + (size_t)l * 512 * 512;
    bt[idx] = bplane(W[kk * 512 + n], inner);
}
// W_cb: Bt [640][3072], rows >=576 zero
__global__ void k_pack_cb3(const float* __restrict__ w, unsigned short* __restrict__ bt)
{
    const int idx = blockIdx.x * 256 + threadIdx.x;   // 640*3072
    if (idx >= 640 * 3072) return;
    const int n = idx / 3072, k = idx - n * 3072;
    const int seg = k >> 9, kk = k & 511;
    const float v = (n < 576) ? w[kk * 576 + n] : 0.f;
    bt[idx] = bplane(v, seg);
}

// ---------------- zero conv guard rows ----------------
__global__ void k_zero_guards(unsigned short* __restrict__ xdp, unsigned short* __restrict__ hp)
{
    const int idx = blockIdx.x * 256 + threadIdx.x;   // 8192
    if (idx >= 8192) return;
    const int b = idx >> 10, rem = idx & 1023;
    const int row = (rem >> 9) ? (NF + 1) : 0;
    const int c = rem & 511;
    const size_t o = ((size_t)b * NFP + row) * 512 + c;
    xdp[o] = 0; hp[o] = 0;
}

// ---------------- encoder MFMA GEMM: segmented-K split-3, A-plane-grouped ----------------
// Logical K = 512 per segment; segments share A planes per pattern {0,0,1,0,1,2}.
// Grouped by A plane: G0(A=g0): segs {0,1,3}  G1(A=g1): {2,4}  G2(A=g2): {5}
//                     G3(A=x0): {6,7,9}       G4(A=x1): {8,10} G5(A=x2): {11}
// -> one A stage serves up to 3 B segments: 18 tile-stages & 6 barrier-pairs per
// 32-wide K chunk instead of 24 & 12. All segs accumulate into the same acc.
// OUTE: 0 = split3 planes [M,512]; 1 = f32 [M,N] col-guarded.
template <int NSEG, int OUTE>
__global__ __launch_bounds__(256)
void k_mm_enc(const unsigned short* __restrict__ g0, const unsigned short* __restrict__ g1,
              const unsigned short* __restrict__ g2, const unsigned short* __restrict__ xA0,
              const unsigned short* __restrict__ xA1, const unsigned short* __restrict__ xA2,
              const unsigned short* __restrict__ Bt, const float* __restrict__ bias,
              void* __restrict__ C0, void* __restrict__ C1, void* __restrict__ C2, int N)
{
    constexpr int K = NSEG * 512;
    constexpr int NGRP = (NSEG == 12) ? 6 : 3;
    __shared__ __align__(16) short As[128 * 32];
    __shared__ __align__(16) short Bs[3][128 * 32];

    int bx, by;
    xcd_swizzle(bx, by);
    const int t  = threadIdx.x;
    const int m0 = by * 128;
    const int n0 = bx * 128;
    const int w  = t >> 6, l = t & 63;
    const int wr = w >> 1, wc = w & 1;
    const int lr = l & 15, lq = l >> 4;

    f32x4 acc[4][4];
#pragma unroll
    for (int i = 0; i < 4; ++i)
#pragma unroll
        for (int j = 0; j < 4; ++j)
#pragma unroll
            for (int r = 0; r < 4; ++r) acc[i][j][r] = 0.f;

    const unsigned short* const APL[6] = {g0, g1, g2, xA0, xA1, xA2};
    constexpr int SB[7]  = {0, 3, 5, 6, 9, 11, 12};                 // group -> seg-list range
    constexpr int SL[12] = {0, 1, 3, 2, 4, 5, 6, 7, 9, 8, 10, 11};  // seg list, grouped

#pragma unroll 1
    for (int kk = 0; kk < 512; kk += 32) {
#pragma unroll
        for (int grp = 0; grp < NGRP; ++grp) {
            const unsigned short* Ab = APL[grp];
            const int ns = SB[grp + 1] - SB[grp];
#pragma unroll
            for (int half = 0; half < 2; ++half) {
                const int ch = (half << 8) + t;
                const int row = ch >> 2, kq = ch & 3;
                load16(Ab + (size_t)(m0 + row) * 512 + kk + kq * 8, &As[ch * 8]);
#pragma unroll
                for (int s = 0; s < 3; ++s) {
                    if (s < ns) {
                        const int seg = SL[SB[grp] + s];
                        load16(Bt + (size_t)(n0 + row) * K + seg * 512 + kk + kq * 8,
                               &Bs[s][ch * 8]);
                    }
                }
            }
            __syncthreads();
            bf16x8 aF[4];
#pragma unroll
            for (int i = 0; i < 4; ++i)
                aF[i] = *(const bf16x8*)&As[(wr * 64 + i * 16 + lr) * 32 + lq * 8];
#pragma unroll
            for (int s = 0; s < 3; ++s) {
                if (s < ns) {
                    bf16x8 bF[4];
#pragma unroll
                    for (int j = 0; j < 4; ++j)
                        bF[j] = *(const bf16x8*)&Bs[s][(wc * 64 + j * 16 + lr) * 32 + lq * 8];
#pragma unroll
                    for (int i = 0; i < 4; ++i)
#pragma unroll
                        for (int j = 0; j < 4; ++j)
                            acc[i][j] = __builtin_amdgcn_mfma_f32_16x16x32_bf16(aF[i], bF[j],
                                                                                acc[i][j], 0, 0, 0);
                }
            }
            __syncthreads();
        }
    }

#pragma unroll
    for (int i = 0; i < 4; ++i) {
#pragma unroll
        for (int r = 0; r < 4; ++r) {
            const int m = m0 + wr * 64 + i * 16 + lq * 4 + r;
#pragma unroll
            for (int j = 0; j < 4; ++j) {
                const int n = n0 + wc * 64 + j * 16 + lr;
                if (OUTE == 0) {
                    const float v = acc[i][j][r] + bias[n];
                    unsigned short u0, u1, u2; split3(v, u0, u1, u2);
                    const size_t ob = (size_t)m * 512 + n;
                    ((unsigned short*)C0)[ob] = u0;
                    ((unsigned short*)C1)[ob] = u1;
                    ((unsigned short*)C2)[ob] = u2;
                } else {
                    if (n < N) ((float*)C0)[(size_t)m * N + n] = acc[i][j][r] + bias[n];
                }
            }
        }
    }
}

// ---------------- decoder MFMA GEMM (XCD-swizzled) ----------------
// AMODE: 0 dense bf16 [M,K]    1 padded-dense (stride 512)    2 conv virtual (stride 512, taps)
// OUT:   0 bf16 [M,512]        1 f32 [M,N] col-guarded        2 bf16 padded [*,512]
template <int AMODE, int OUT>
__global__ __launch_bounds__(256)
void k_mm(const unsigned short* __restrict__ a0, const unsigned short* __restrict__ Bt,
          const float* __restrict__ bias, void* __restrict__ C0, int N, int K)
{
    __shared__ __align__(16) short As[128 * 32];
    __shared__ __align__(16) short Bs[128 * 32];

    int bx, by;
    xcd_swizzle(bx, by);
    const int t  = threadIdx.x;
    const int m0 = by * 128;
    const int n0 = bx * 128;
    const int w  = t >> 6, l = t & 63;
    const int wr = w >> 1, wc = w & 1;
    const int lr = l & 15, lq = l >> 4;

    f32x4 acc[4][4];
#pragma unroll
    for (int i = 0; i < 4; ++i)
#pragma unroll
        for (int j = 0; j < 4; ++j)
#pragma unroll
            for (int r = 0; r < 4; ++r) acc[i][j][r] = 0.f;

    for (int k0 = 0; k0 < K; k0 += 32) {
#pragma unroll
        for (int half = 0; half < 2; ++half) {
            const int ch = (half << 8) + t;
            const int row = ch >> 2, kq = ch & 3;
            const int m = m0 + row;
            const unsigned short* ga;
            if (AMODE == 0) {
                ga = a0 + (size_t)m * K + k0 + kq * 8;
            } else if (AMODE == 1) {
                ga = a0 + (((size_t)(m + ((m >> 12) << 1) + 1)) << 9) + k0 + kq * 8;
            } else {
                const int tap = k0 >> 9;
                ga = a0 + (((size_t)(m + ((m >> 12) << 1) + tap)) << 9) + (k0 & 511) + kq * 8;
            }
            load16(ga, &As[ch * 8]);
            load16(Bt + (size_t)(n0 + row) * K + k0 + kq * 8, &Bs[ch * 8]);
        }
        __syncthreads();

        bf16x8 aF[4], bF[4];
#pragma unroll
        for (int i = 0; i < 4; ++i) {
            aF[i] = *(const bf16x8*)&As[(wr * 64 + i * 16 + lr) * 32 + lq * 8];
            bF[i] = *(const bf16x8*)&Bs[(wc * 64 + i * 16 + lr) * 32 + lq * 8];
        }
#pragma unroll
        for (int i = 0; i < 4; ++i)
#pragma unroll
            for (int j = 0; j < 4; ++j)
                acc[i][j] = __builtin_amdgcn_mfma_f32_16x16x32_bf16(aF[i], bF[j], acc[i][j], 0, 0, 0);
        __syncthreads();
    }

#pragma unroll
    for (int i = 0; i < 4; ++i) {
#pragma unroll
        for (int r = 0; r < 4; ++r) {
            const int m = m0 + wr * 64 + i * 16 + lq * 4 + r;
#pragma unroll
            for (int j = 0; j < 4; ++j) {
                const int n = n0 + wc * 64 + j * 16 + lr;
                const float bv = (OUT == 1) ? ((n < N) ? bias[n] : 0.f) : bias[n];
                const float v = acc[i][j][r] + bv;
                if (OUT == 0) {
                    ((unsigned short*)C0)[(size_t)m * 512 + n] = f2bu(v);
                } else if (OUT == 1) {
                    if (n < N) ((float*)C0)[(size_t)m * N + n] = v;
                } else {
                    ((unsigned short*)C0)[((size_t)(m + ((m >> 12) << 1) + 1)) * 512 + n] = f2bu(v);
                }
            }
        }
    }
}

// ---------------- GroupNorm stats ----------------
__global__ __launch_bounds__(256)
void k_gn_stats(const unsigned short* __restrict__ h, float* __restrict__ stats)
{
    const int bg = blockIdx.x;      // 0..63
    const int b = bg >> 3, g = bg & 7;
    const int t = threadIdx.x;
    float sum = 0.f, sq = 0.f;
    const unsigned short* base = h + (size_t)b * NF * 512 + g * 64;
    for (int n = t; n < NF; n += 256) {
        const unsigned short* p = base + (size_t)n * 512;
#pragma unroll
        for (int c = 0; c < 64; c += 4) {
            const ushort4 v4 = *(const ushort4*)(p + c);
            const float f0 = b2f(v4.x), f1 = b2f(v4.y), f2 = b2f(v4.z), f3 = b2f(v4.w);
            sum += f0 + f1 + f2 + f3;
            sq  += f0 * f0 + f1 * f1 + f2 * f2 + f3 * f3;
        }
    }
    __shared__ float s1[256], s2[256];
    s1[t] = sum; s2[t] = sq;
    __syncthreads();
    for (int o = 128; o > 0; o >>= 1) {
        if (t < o) { s1[t] += s1[t + o]; s2[t] += s2[t + o]; }
        __syncthreads();
    }
    if (t == 0) {
        const float cntf = (float)(NF * 64);
        const float mean = s1[0] / cntf;
        const float var  = s2[0] / cntf - mean * mean;
        stats[bg * 2 + 0] = mean;
        stats[bg * 2 + 1] = rsqrtf(var + 1e-5f);
    }
}

// ---------------- GN affine + SiLU (+ residual), write padded bf16 ----------------
__global__ void k_gn_apply(const unsigned short* __restrict__ h, const float* __restrict__ stats,
                           const float* __restrict__ gamma, const float* __restrict__ beta,
                           const unsigned short* __restrict__ resid_pad, unsigned short* __restrict__ dst_pad)
{
    const int idx = blockIdx.x * 256 + threadIdx.x;
    if (idx >= NFACE * 512 / 4) return;
    const int i4 = idx * 4;
    const int c = i4 & 511;
    const int row = i4 >> 9;
    const int b = row >> 12;
    const int g = c >> 6;
    const float mean = stats[(b * 8 + g) * 2 + 0];
    const float rstd = stats[(b * 8 + g) * 2 + 1];
    const ushort4 v4 = *(const ushort4*)(h + (size_t)row * 512 + c);
    const float4 gm = *(const float4*)&gamma[c];
    const float4 bt = *(const float4*)&beta[c];
    float o0 = (b2f(v4.x) - mean) * rstd * gm.x + bt.x;
    float o1 = (b2f(v4.y) - mean) * rstd * gm.y + bt.y;
    float o2 = (b2f(v4.z) - mean) * rstd * gm.z + bt.z;
    float o3 = (b2f(v4.w) - mean) * rstd * gm.w + bt.w;
    o0 = o0 / (1.f + expf(-o0));
    o1 = o1 / (1.f + expf(-o1));
    o2 = o2 / (1.f + expf(-o2));
    o3 = o3 / (1.f + expf(-o3));
    const size_t po = ((size_t)row + (size_t)(row >> 12) * 2 + 1) * 512 + c;
    if (resid_pad) {
        const ushort4 r4 = *(const ushort4*)(resid_pad + po);
        o0 += b2f(r4.x); o1 += b2f(r4.y); o2 += b2f(r4.z); o3 += b2f(r4.w);
    }
    ushort4 o;
    o.x = f2bu(o0); o.y = f2bu(o1); o.z = f2bu(o2); o.w = f2bu(o3);
    *(ushort4*)(dst_pad + po) = o;
}

// ---------------- launch ----------------
extern "C" void kernel_launch(void* const* d_in, const int* in_sizes, int n_in,
                              void* d_out, int out_size, void* d_ws, size_t ws_size,
                              hipStream_t stream)
{
    const float* vertices   = (const float*)d_in[0];
    const int*   faces      = (const int*)  d_in[1];
    const int*   face_edges = (const int*)  d_in[2];
    const float* coor_embed = (const float*)d_in[5];
    const float* W_in    = (const float*)d_in[6];
    const float* b_in    = (const float*)d_in[7];
    const float* sage_Wl = (const float*)d_in[8];
    const float* sage_Wr = (const float*)d_in[9];
    const float* sage_b  = (const float*)d_in[10];
    const float* W_cb    = (const float*)d_in[11];
    const float* b_cb    = (const float*)d_in[12];
    const float* lfq_in  = (const float*)d_in[13];
    const float* lfq_out = (const float*)d_in[14];
    const float* W_out   = (const float*)d_in[15];
    const float* b_out   = (const float*)d_in[16];
    const float* dconv_w = (const float*)d_in[17];
    const float* dconv_b = (const float*)d_in[18];
    const float* dgn_g   = (const float*)d_in[19];
    const float* dgn_b   = (const float*)d_in[20];
    const float* W_log   = (const float*)d_in[21];
    const float* b_log   = (const float*)d_in[22];

    char* base = (char*)d_ws;
    size_t off = 0;
    auto alloc = [&](size_t bytes) { char* p = base + off; off += (bytes + 255) & ~(size_t)255; return p; };

    const size_t PLANE  = (size_t)NFACE * 512 * 2;      // 33,554,432 B
    // P3 must also host xdp+hp+cbuf = 2*BB*NFP*512*2 + PLANE = 100,696,064 B
    // which exceeds 3*PLANE by exactly 32 KB (NFP guard rows) -> explicit slack.
    char* P1 = alloc(3 * PLANE);                        // x planes | layer2 out
    char* P2 = alloc(3 * PLANE);                        // g planes | feo@0 | avg+quant@40M
    char* P3 = alloc(3 * PLANE + 65536);                // y planes | fe f32 | xdp+hp+cbuf

    unsigned short* x0 = (unsigned short*)P1;
    unsigned short* x1 = x0 + (size_t)NFACE * 512;
    unsigned short* x2 = x1 + (size_t)NFACE * 512;
    unsigned short* g0 = (unsigned short*)P2;
    unsigned short* g1 = g0 + (size_t)NFACE * 512;
    unsigned short* g2 = g1 + (size_t)NFACE * 512;
    unsigned short* y0 = (unsigned short*)P3;
    unsigned short* y1 = y0 + (size_t)NFACE * 512;
    unsigned short* y2 = y1 + (size_t)NFACE * 512;
    float*          fe   = (float*)P3;                              // phase 6-7
    unsigned short* feo  = (unsigned short*)P2;                     // phase >=8
    float*          avg  = (float*)(P2 + (size_t)40 * 1024 * 1024); // 12.6M
    float*          quant = avg + (size_t)NVB * 192;                // 12.6M
    unsigned short* xdp  = (unsigned short*)P3;                     // decoder
    unsigned short* hp   = xdp + (size_t)BB * NFP * 512;
    unsigned short* cbuf = hp + (size_t)BB * NFP * 512;

    int*   fc = (int*)  alloc((size_t)NFACE * 12 * 4);
    float* T  = (float*)alloc((size_t)9 * 128 * 512 * 4);
    unsigned short* bt_sage = (unsigned short*)alloc(2ull * 512 * 6144 * 2);
    unsigned short* bt_cb   = (unsigned short*)alloc(640ull * 3072 * 2);
    unsigned short* bt_out  = (unsigned short*)alloc(512ull * 576 * 2);
    unsigned short* bt_log  = (unsigned short*)alloc(1152ull * 512 * 2);
    unsigned short* bt_conv = (unsigned short*)alloc(4ull * 512 * 1536 * 2);
    int* degE = (int*)alloc(32768 * 4);
    int* rsE  = (int*)alloc(32772 * 4);
    int* curE = (int*)alloc(32768 * 4);
    int* srcE = (int*)alloc(98304 * 4);
    int* degV = (int*)alloc(16384 * 4);
    int* rsV  = (int*)alloc(16388 * 4);
    int* curV = (int*)alloc(16384 * 4);
    int* cidV = (int*)alloc(98304 * 4);
    float* stats = (float*)alloc(128 * 4);

    const dim3 blk(256);

    // ---- weight packing ----
    k_pack_sage3<<<dim3(24576), blk, 0, stream>>>(sage_Wl, sage_Wr, bt_sage);
    k_pack_cb3  <<<dim3(7680),  blk, 0, stream>>>(W_cb, bt_cb);
    k_pack_plain<<<dim3(1152),  blk, 0, stream>>>(W_out, bt_out, 576, 512);
    k_pack_plain<<<dim3(2304),  blk, 0, stream>>>(W_log, bt_log, 512, 1152);
    k_pack_conv <<<dim3(12288), blk, 0, stream>>>(dconv_w, bt_conv);

    // ---- CSR builds ----
    hipMemsetAsync(degE, 0, 32768 * 4, stream);
    hipMemsetAsync(degV, 0, 16384 * 4, stream);
    k_count_e<<<dim3(384), blk, 0, stream>>>(face_edges, degE);
    k_count_v<<<dim3(384), blk, 0, stream>>>(faces, degV);
    k_scan<<<dim3(1), blk, 0, stream>>>(degE, rsE, curE, 32768);
    k_scan<<<dim3(1), blk, 0, stream>>>(degV, rsV, curV, 16384);
    k_fill_e<<<dim3(384), blk, 0, stream>>>(face_edges, curE, srcE);
    k_fill_v<<<dim3(384), blk, 0, stream>>>(faces, curV, cidV);

    // ---- x = emb @ W_in + b_in (exact table trick) -> 3 planes ----
    k_codes<<<dim3(1152), blk, 0, stream>>>(vertices, faces, fc);
    k_build_T<<<dim3(9, 128), blk, 0, stream>>>(coor_embed, W_in, T);
    k_xin<<<dim3(NFACE), blk, 0, stream>>>(fc, T, b_in, x0, x1, x2);

    // ---- SAGE layer 1: y = agg(x)@Wl + x@Wr + b (split-3 MFMA, K=6144) ----
    k_agg_e3<<<dim3(16384), blk, 0, stream>>>(x0, x1, x2, rsE, srcE, g0, g1, g2);
    k_mm_enc<12, 0><<<dim3(4, 256), blk, 0, stream>>>(g0, g1, g2, x0, x1, x2,
        bt_sage, sage_b, y0, y1, y2, 512);

    // ---- SAGE layer 2: x = agg(y)@Wl + y@Wr + b ----
    k_agg_e3<<<dim3(16384), blk, 0, stream>>>(y0, y1, y2, rsE, srcE, g0, g1, g2);
    k_mm_enc<12, 0><<<dim3(4, 256), blk, 0, stream>>>(g0, g1, g2, y0, y1, y2,
        bt_sage + (size_t)512 * 6144, sage_b + 512, x0, x1, x2, 512);

    // ---- fe = x @ W_cb + b_cb (split-3 MFMA, K=3072) -> f32 ----
    k_mm_enc<6, 1><<<dim3(5, 256), blk, 0, stream>>>(x0, x1, x2, nullptr, nullptr, nullptr,
        bt_cb, b_cb, fe, nullptr, nullptr, 576);

    // ---- vertex mean + LFQ + gather ----
    k_agg_verts<<<dim3(NVB), dim3(192), 0, stream>>>(fe, rsV, cidV, avg);
    k_lfq<<<dim3(NVB), dim3(64), 0, stream>>>(avg, lfq_in, lfq_out, quant);
    k_gather_feo<<<dim3(73728), blk, 0, stream>>>(quant, faces, feo);

    // ---- decoder (bf16 MFMA) ----
    k_zero_guards<<<dim3(32), blk, 0, stream>>>(xdp, hp);
    k_mm<0, 2><<<dim3(4, 256), blk, 0, stream>>>(feo, bt_out, b_out, xdp, 512, 576);

    for (int blkI = 0; blkI < 2; ++blkI) {
        k_mm<2, 0><<<dim3(4, 256), blk, 0, stream>>>(xdp,
            bt_conv + (size_t)(blkI * 2 + 0) * 512 * 1536, dconv_b + (blkI * 2 + 0) * 512,
            cbuf, 512, 1536);
        k_gn_stats<<<dim3(64), blk, 0, stream>>>(cbuf, stats);
        k_gn_apply<<<dim3(16384), blk, 0, stream>>>(cbuf, stats,
            dgn_g + (blkI * 2 + 0) * 512, dgn_b + (blkI * 2 + 0) * 512, nullptr, hp);
        k_mm<2, 0><<<dim3(4, 256), blk, 0, stream>>>(hp,
            bt_conv + (size_t)(blkI * 2 + 1) * 512 * 1536, dconv_b + (blkI * 2 + 1) * 512,
            cbuf, 512, 1536);
        k_gn_stats<<<dim3(64), blk, 0, stream>>>(cbuf, stats);
        k_gn_apply<<<dim3(16384), blk, 0, stream>>>(cbuf, stats,
            dgn_g + (blkI * 2 + 1) * 512, dgn_b + (blkI * 2 + 1) * 512, xdp, xdp);
    }

    // ---- logits ----
    k_mm<1, 1><<<dim3(9, 256), blk, 0, stream>>>(xdp, bt_log, b_log, (float*)d_out, 1152, 512);
}